// Round 1
// 1359.688 us; speedup vs baseline: 1.2204x; 1.2204x over previous
//
#include <hip/hip_runtime.h>
#include <hip/hip_bf16.h>
#include <hip/hip_fp16.h>

typedef unsigned int uint32;
typedef _Float16 hf2 __attribute__((ext_vector_type(2)));

#define NT 1024

// ---------- helpers ----------
__device__ __forceinline__ float bfu(unsigned short v) { return __uint_as_float(((uint32)v) << 16); }
__device__ __forceinline__ unsigned short f2bf(float f) {
    uint32 u = __float_as_uint(f);
    u = (u + 0x7fffu + ((u >> 16) & 1u)) >> 16;
    return (unsigned short)u;
}
__device__ __forceinline__ uint32 pack_f16(float a, float b) {
    __half ha = __float2half_rn(a), hb = __float2half_rn(b);
    return (uint32)__half_as_ushort(ha) | ((uint32)__half_as_ushort(hb) << 16);
}
__device__ __forceinline__ float fexp2(float x) {
#if __has_builtin(__builtin_amdgcn_exp2f)
    return __builtin_amdgcn_exp2f(x);
#else
    return exp2f(x);
#endif
}
__device__ __forceinline__ float frcp(float x) {
#if __has_builtin(__builtin_amdgcn_rcpf)
    return __builtin_amdgcn_rcpf(x);
#else
    return __fdividef(1.f, x);
#endif
}
// tanh = 1 - 2/(1+e^{2x}); saturates correctly at +-inf/overflow, no clamp needed.
__device__ __forceinline__ float fast_tanh(float x) {
    float e = fexp2(x * 2.8853900817779268f);  // 2*log2(e)
    return fmaf(-2.f, frcp(1.f + e), 1.f);
}
__device__ __forceinline__ float fast_sigmoid(float x) {
    return frcp(1.f + fexp2(-1.4426950408889634f * x));
}
// broadcast lane k's value (k wave-uniform) without DS traffic
__device__ __forceinline__ float rdlane(float v, int k) {
#if __has_builtin(__builtin_amdgcn_readlane)
    return __builtin_bit_cast(float, __builtin_amdgcn_readlane(__builtin_bit_cast(int, v), k));
#else
    return __shfl(v, k);
#endif
}
// 2-way f16 dot with f32 accumulate (v_dot2_f32_f16), guarded fallback
__device__ __forceinline__ float fdot2(uint32 w, uint32 v, float acc) {
#if __has_builtin(__builtin_amdgcn_fdot2)
    return __builtin_amdgcn_fdot2(__builtin_bit_cast(hf2, w), __builtin_bit_cast(hf2, v), acc, false);
#else
    __half2 wh = __builtin_bit_cast(__half2, w), vh = __builtin_bit_cast(__half2, v);
    float2 wf = __half22float2(wh), vf = __half22float2(vh);
    return fmaf(wf.y, vf.y, fmaf(wf.x, vf.x, acc));
#endif
}

// LDS flag ops (workgroup scope: ds ops only, no cache maintenance)
// S = s_sleep length between polls: 1 for chain-critical wakes, 4 for slack-rich waves
template <int S>
__device__ __forceinline__ void spin_ge(uint32* p, uint32 tgt) {
    int guard = 0;
    while (__hip_atomic_load(p, __ATOMIC_ACQUIRE, __HIP_MEMORY_SCOPE_WORKGROUP) < tgt) {
        __builtin_amdgcn_s_sleep(S);
        if (++guard > (1 << 22)) break;  // safety valve: wrong answer beats a hang
    }
}
__device__ __forceinline__ void st_flag(uint32* p, uint32 v) {
    __hip_atomic_store(p, v, __ATOMIC_RELEASE, __HIP_MEMORY_SCOPE_WORKGROUP);
}
__device__ __forceinline__ void add_flag(uint32* p, uint32 v) {
    __hip_atomic_fetch_add(p, v, __ATOMIC_RELEASE, __HIP_MEMORY_SCOPE_WORKGROUP);
}

// ---------- prep 1: f16-convert + re-layout weights ----------
__global__ void prep_weights(const float* __restrict__ We, const float* __restrict__ W_ih,
                             const float* __restrict__ W_hh, uint32* __restrict__ We2,
                             uint32* __restrict__ Wc2) {
    int idx = blockIdx.x * 256 + threadIdx.x;
    if (idx < 32768) {
        int p = idx & 3, s = (idx >> 2) & 127, jq = idx >> 9;
        int j = 8 * jq + 2 * p;
        We2[idx] = pack_f16(We[s * 512 + j], We[s * 512 + j + 1]);
    } else if (idx < 229376) {
        int i2 = idx - 32768;
        int p = i2 & 3, q = (i2 >> 2) & 255, np = i2 >> 10;
        int g = 4 * q + p;
        int n0 = 2 * np, n1 = 2 * np + 1;
        float w0, w1;
        if (n0 < 128) {
            w0 = W_ih[g * 128 + n0];
            w1 = W_ih[g * 128 + n1];
        } else {
            w0 = W_hh[g * 256 + (n0 - 128)];
            w1 = W_hh[g * 256 + (n1 - 128)];
        }
        Wc2[i2] = pack_f16(w0, w1);
    }
}

// ---------- prep 2: Ux[b,s,n] = sum_t x[b,t,n] * Ue[s,t]  (bf16 out) ----------
__global__ void ux_kernel(const float* __restrict__ x, const float* __restrict__ Ue,
                          unsigned short* __restrict__ Uxg) {
    int b = blockIdx.x >> 1, h = blockIdx.x & 1;
    int n = threadIdx.x & 127, sg = threadIdx.x >> 7;
    int s0 = h * 64 + sg * 16;
    float acc[16];
#pragma unroll
    for (int k = 0; k < 16; ++k) acc[k] = 0.f;
    for (int t0 = 0; t0 < 128; t0 += 16) {
        float xv[16];
#pragma unroll
        for (int tt = 0; tt < 16; ++tt) xv[tt] = x[(b * 128 + t0 + tt) * 128 + n];
#pragma unroll
        for (int k = 0; k < 16; ++k) {
            const float4* uep = (const float4*)(Ue + (s0 + k) * 128 + t0);
            float4 u0 = uep[0], u1 = uep[1], u2 = uep[2], u3 = uep[3];
            acc[k] += xv[0] * u0.x + xv[1] * u0.y + xv[2] * u0.z + xv[3] * u0.w
                    + xv[4] * u1.x + xv[5] * u1.y + xv[6] * u1.z + xv[7] * u1.w
                    + xv[8] * u2.x + xv[9] * u2.y + xv[10] * u2.z + xv[11] * u2.w
                    + xv[12] * u3.x + xv[13] * u3.y + xv[14] * u3.z + xv[15] * u3.w;
        }
    }
#pragma unroll
    for (int k = 0; k < 16; ++k)
        Uxg[b * 16384 + (s0 + k) * 128 + n] = f2bf(acc[k]);
}

// ---------- main: 128 blocks, wave-specialized, barrier-free step loop ----------
// A-waves (tid<768): 6 groups of 128 threads; thread owns gate-octet ol (gates
//   8ol..8ol+7). Groups 0-3 (prio 0): h-part K-chunks (start on cnt5>=4t, slow poll).
//   Groups 4,5 (prio 1): attention ph1 (WeQ stream) -> cnt1, then xw-part (on xw_flag).
// B-waves (tid>=768, 256 thr, prio 2): cnt1 -> web (per-wave regs) -> ph2 tanh ->
//   cnt2; wave12: ph3 softmax (no max-sub; scores bounded) -> xw_flag; all: cnt4 ->
//   ph5 gate-reduce+pointwise -> cnt5 (A-waves spin cnt5 directly; no relay).
__global__ __launch_bounds__(NT, 4)
void encoder_kernel(const float* __restrict__ x, const float* __restrict__ v_e,
                    const float* __restrict__ b_ih, const float* __restrict__ b_hh,
                    const unsigned short* __restrict__ Uxg, const uint4* __restrict__ We2q,
                    const uint4* __restrict__ Wc2q, float* __restrict__ out) {
    __shared__ __align__(16) unsigned short Ux_s[16384];  // 32 KB [s][n] bf16
    __shared__ __align__(16) float part4[6144];           // 24 KB [grp][1024 gates]
    __shared__ float part1[256];                          // [jg][s]
    __shared__ float part2[256];                          // [sg][n]
    __shared__ __align__(16) uint32 vh_s[192];   // half2 pairs of v=[xw(0..64)|h(64..192)]
    __shared__ __align__(16) uint32 hsh_s[256];  // half2 pairs of hs=[h(0..128)|c(128..256)]
    __shared__ float c_s[256];                   // f32 c state
    __shared__ __align__(16) float bias_s[1024];
    __shared__ uint32 xw_flag, cnt1, cnt2, cnt4, cnt5;
    __shared__ float pad_force[4096];  // LDS pad -> 1 block/CU

    const int tid = threadIdx.x;
    const int b = blockIdx.x;

    {   // load this batch's Ux tile (coalesced)
        const uint4* src = (const uint4*)(Uxg + b * 16384);
        uint4* dst = (uint4*)Ux_s;
        for (int i = tid; i < 2048; i += NT) dst[i] = src[i];
    }
    bias_s[tid] = b_ih[tid] + b_hh[tid];
    if (tid < 192) vh_s[tid] = 0u;
    if (tid < 256) { hsh_s[tid] = 0u; c_s[tid] = 0.f; }
    if (tid == 0) { xw_flag = 0; cnt1 = 0; cnt2 = 0; cnt4 = 0; cnt5 = 0; }
    __syncthreads();  // the only barrier; all threads reach it

// 4-np block: one ds_read_b128 of v-pairs + 8 b128 weight loads + 32 fdot2
#define NP_BLOCK(npb)                                                \
    {                                                                \
        uint4 vp4 = *(const uint4*)&vh_s[(npb)];                     \
        _Pragma("unroll")                                            \
        for (int u = 0; u < 4; ++u) {                                \
            uint32 vp = (&vp4.x)[u];                                 \
            const uint4* wp = wc + ((npb) + u) * 256;                \
            uint4 w0 = wp[0], w1 = wp[1];                            \
            a0 = fdot2(w0.x, vp, a0); a1 = fdot2(w0.y, vp, a1);      \
            a2 = fdot2(w0.z, vp, a2); a3 = fdot2(w0.w, vp, a3);      \
            a4 = fdot2(w1.x, vp, a4); a5 = fdot2(w1.y, vp, a5);      \
            a6 = fdot2(w1.z, vp, a6); a7 = fdot2(w1.w, vp, a7);      \
        }                                                            \
    }

    if (tid < 768) {
        // ================= A-group =================
        const int ol = tid & 127, g = tid >> 7;
        if (g >= 4) __builtin_amdgcn_s_setprio(1);  // ph1/xw are chain phases
        const uint4* wc = Wc2q + 2 * ol;
        for (int t = 0; t < 128; ++t) {
            float a0 = 0.f, a1 = 0.f, a2 = 0.f, a3 = 0.f;
            float a4 = 0.f, a5 = 0.f, a6 = 0.f, a7 = 0.f;
            if (g < 4) {
                // h-part has thousands of cycles of slack: cheap slow polls
                spin_ge<4>(&cnt5, (uint32)(4 * t));
                const int np0 = 64 + g * 32;
#pragma unroll 2
                for (int i = 0; i < 8; ++i) NP_BLOCK(np0 + 4 * i);
            } else {
                spin_ge<1>(&cnt5, (uint32)(4 * t));
                // ph1: web partial over hs-chunk jg
                const int s = ol, jg = g - 4;
                float acc = 0.f;
#pragma unroll 4
                for (int jq = jg * 32; jq < jg * 32 + 32; ++jq) {
                    uint4 w = We2q[jq * 128 + s];
                    uint4 hh = *(const uint4*)&hsh_s[4 * jq];
                    acc = fdot2(w.x, hh.x, acc);
                    acc = fdot2(w.y, hh.y, acc);
                    acc = fdot2(w.z, hh.z, acc);
                    acc = fdot2(w.w, hh.w, acc);
                }
                part1[jg * 128 + s] = acc;
                if ((tid & 63) == 0) add_flag(&cnt1, 1);
                // xw-part: np in [32(g-4), 32(g-4)+32) -- chain tail, fast wake
                spin_ge<1>(&xw_flag, (uint32)(t + 1));
                const int np0 = jg * 32;
#pragma unroll 2
                for (int i = 0; i < 8; ++i) NP_BLOCK(np0 + 4 * i);
            }
            float4* p4 = (float4*)&part4[g * 1024 + 8 * ol];
            p4[0] = make_float4(a0, a1, a2, a3);
            p4[1] = make_float4(a4, a5, a6, a7);
            if ((tid & 63) == 0) add_flag(&cnt4, 1);
        }
    } else {
        // ================= B-group =================
        __builtin_amdgcn_s_setprio(2);  // B is on the chain almost always
        const int bt = tid - 768, l = tid & 63;
        const int n = bt & 127, sg = bt >> 7;
        const float ve_lane = v_e[sg * 64 + l];  // lane l holds ve[sg*64+l]
        const unsigned short* uxrow = Ux_s + sg * 64 * 128 + n;
        for (int t = 0; t < 128; ++t) {
            float2 xt2;
            if (bt < 64) xt2 = *(const float2*)(x + (b * 128 + t) * 128 + 2 * l);
            spin_ge<1>(&cnt1, (uint32)(4 * (t + 1)));
            // per-wave redundant web (no extra sync): lane l holds web[l], web[64+l]
            float web_lo = part1[l] + part1[128 + l];
            float web_hi = part1[64 + l] + part1[192 + l];
            float wsel = sg ? web_hi : web_lo;
            // ph2: scores partial over s-chunk sg (readlane broadcast, 5-op tanh)
            float acc = 0.f;
#pragma unroll
            for (int k = 0; k < 64; ++k) {
                float wv = rdlane(wsel, k);
                float vek = rdlane(ve_lane, k);
                float a = wv + bfu(uxrow[k * 128]);
                acc = fmaf(vek, fast_tanh(a), acc);
            }
            part2[sg * 128 + n] = acc;
            if (l == 0) add_flag(&cnt2, 1);
            if (bt < 64) {
                // ph3: softmax + xw (wave 12 only); lane l owns n=2l, 2l+1
                spin_ge<1>(&cnt2, (uint32)(4 * (t + 1)));
                __builtin_amdgcn_s_setprio(3);
                float v0 = part2[2 * l] + part2[128 + 2 * l];
                float v1 = part2[2 * l + 1] + part2[129 + 2 * l];
                // |score| <= sum_s |ve[s]| ~ 6, so raw exp is overflow-safe: no max pass
                float e0 = fexp2(v0 * 1.4426950408889634f);
                float e1 = fexp2(v1 * 1.4426950408889634f);
                float ssum = e0 + e1;
#pragma unroll
                for (int off = 32; off > 0; off >>= 1) ssum += __shfl_xor(ssum, off);
                float inv = frcp(ssum);
                vh_s[l] = pack_f16(xt2.x * e0 * inv, xt2.y * e1 * inv);
                if (bt == 0) st_flag(&xw_flag, (uint32)(t + 1));
                __builtin_amdgcn_s_setprio(2);
            }
            // ph5: gate reduce + LSTM pointwise (all 4 B-waves; thread = h-unit j)
            spin_ge<1>(&cnt4, (uint32)(12 * (t + 1)));
            const int j = bt;
            float gi = bias_s[j], gf = bias_s[256 + j];
            float gg = bias_s[512 + j], go = bias_s[768 + j];
#pragma unroll
            for (int gr = 0; gr < 6; ++gr) {
                const float* pp = part4 + gr * 1024;
                gi += pp[j]; gf += pp[256 + j];
                gg += pp[512 + j]; go += pp[768 + j];
            }
            float c = c_s[j];
            float c2 = fast_sigmoid(gf) * c + fast_sigmoid(gi) * fast_tanh(gg);
            float h2v = fast_sigmoid(go) * fast_tanh(c2);
            c_s[j] = c2;
            float hn = __shfl_xor(h2v, 1);
            float cn = __shfl_xor(c2, 1);
            if (!(j & 1)) {
                uint32 hp = pack_f16(h2v, hn);
                vh_s[64 + (j >> 1)] = hp;       // v h-pairs for gate GEMV
                hsh_s[j >> 1] = hp;             // hs h-pairs for ph1
                hsh_s[128 + (j >> 1)] = pack_f16(c2, cn);  // hs c-pairs
            }
            if (l == 0) add_flag(&cnt5, 1);     // A-waves spin on cnt5 directly
            // global store AFTER the release: keep its vmcnt off the handoff path
            out[(t * 128 + b) * 256 + j] = h2v;
        }
        // keep pad_force alive (never true at runtime)
        if (__hip_atomic_load(&cnt5, __ATOMIC_RELAXED, __HIP_MEMORY_SCOPE_WORKGROUP) == 0xffffffffu)
            pad_force[tid & 4095] = 0.f;
    }
#undef NP_BLOCK
}

extern "C" void kernel_launch(void* const* d_in, const int* in_sizes, int n_in,
                              void* d_out, int out_size, void* d_ws, size_t ws_size,
                              hipStream_t stream) {
    const float* x    = (const float*)d_in[0];
    const float* We   = (const float*)d_in[1];
    const float* Ue   = (const float*)d_in[2];
    const float* v_e  = (const float*)d_in[3];
    const float* W_ih = (const float*)d_in[4];
    const float* W_hh = (const float*)d_in[5];
    const float* b_ih = (const float*)d_in[6];
    const float* b_hh = (const float*)d_in[7];
    float* out = (float*)d_out;

    char* w = (char*)d_ws;
    unsigned short* Uxg = (unsigned short*)w;      // 4 MB
    uint32* We2 = (uint32*)(w + 4194304);          // 128 KB
    uint32* Wc2 = (uint32*)(w + 4325376);          // 768 KB

    prep_weights<<<896, 256, 0, stream>>>(We, W_ih, W_hh, We2, Wc2);
    ux_kernel<<<256, 512, 0, stream>>>(x, Ue, Uxg);
    encoder_kernel<<<128, NT, 0, stream>>>(x, v_e, b_ih, b_hh, Uxg,
                                           (const uint4*)We2, (const uint4*)Wc2, out);
}